// Round 1
// baseline (968.653 us; speedup 1.0000x reference)
//
#include <hip/hip_runtime.h>
#include <math.h>

#define BB 4
#define NN 4096
#define MM 256
#define CC 768
#define HH 12
#define DD 64
#define SCALEF 0.125f
#define LN_EPSF 1e-5f

// ---------------------------------------------------------------------------
// out[r][c] = sum_k X[r][k] * W[c][k] + bias[c];  X:[R,768], W:[768,768]
// 64x64 tile, BK=16, 256 threads, 4x4 micro-tile, LDS transposed [k][m]/[k][n]
// ---------------------------------------------------------------------------
__global__ __launch_bounds__(256) void proj_gemm(
    const float* __restrict__ X, const float* __restrict__ W,
    const float* __restrict__ bias, float* __restrict__ out)
{
    const int tid = threadIdx.x;
    const int bm = blockIdx.x, bn = blockIdx.y;
    __shared__ float As[16][64];
    __shared__ float Bs[16][64];
    const int ty = tid >> 4, tx = tid & 15;
    const int lrow = tid >> 2, lk = (tid & 3) << 2;
    const float* Xp = X + (size_t)(bm * 64 + lrow) * CC + lk;
    const float* Wp = W + (size_t)(bn * 64 + lrow) * CC + lk;
    float acc[4][4] = {};
    for (int kk = 0; kk < CC; kk += 16) {
        float4 a  = *(const float4*)(Xp + kk);
        float4 w4 = *(const float4*)(Wp + kk);
        __syncthreads();
        As[lk + 0][lrow] = a.x;  As[lk + 1][lrow] = a.y;
        As[lk + 2][lrow] = a.z;  As[lk + 3][lrow] = a.w;
        Bs[lk + 0][lrow] = w4.x; Bs[lk + 1][lrow] = w4.y;
        Bs[lk + 2][lrow] = w4.z; Bs[lk + 3][lrow] = w4.w;
        __syncthreads();
#pragma unroll
        for (int k = 0; k < 16; ++k) {
            float4 av = *(const float4*)&As[k][ty * 4];
            float4 bv = *(const float4*)&Bs[k][tx * 4];
            float avv[4] = {av.x, av.y, av.z, av.w};
            float bvv[4] = {bv.x, bv.y, bv.z, bv.w};
#pragma unroll
            for (int i = 0; i < 4; ++i)
#pragma unroll
                for (int j = 0; j < 4; ++j)
                    acc[i][j] = fmaf(avv[i], bvv[j], acc[i][j]);
        }
    }
    const float4 b4 = *(const float4*)(bias + bn * 64 + tx * 4);
    const float bvv[4] = {b4.x, b4.y, b4.z, b4.w};
#pragma unroll
    for (int i = 0; i < 4; ++i) {
        float4 o = make_float4(acc[i][0] + bvv[0], acc[i][1] + bvv[1],
                               acc[i][2] + bvv[2], acc[i][3] + bvv[3]);
        *(float4*)(out + (size_t)(bm * 64 + ty * 4 + i) * CC + bn * 64 + tx * 4) = o;
    }
}

// ---------------------------------------------------------------------------
// In-place LayerNorm over rows of 768; optional output scale (Q gets 1/sqrt(D))
// ---------------------------------------------------------------------------
__global__ __launch_bounds__(256) void ln_rows(
    float* __restrict__ Y, const float* __restrict__ g,
    const float* __restrict__ be, const float scale)
{
    const int row = blockIdx.x;
    float* y = Y + (size_t)row * CC;
    const int tid = threadIdx.x;
    float x0 = y[tid], x1 = y[tid + 256], x2 = y[tid + 512];
    float s = x0 + x1 + x2;
    float q = x0 * x0 + x1 * x1 + x2 * x2;
#pragma unroll
    for (int o = 32; o >= 1; o >>= 1) {
        s += __shfl_xor(s, o, 64);
        q += __shfl_xor(q, o, 64);
    }
    __shared__ float sh_s[4], sh_q[4];
    const int w = tid >> 6;
    if ((tid & 63) == 0) { sh_s[w] = s; sh_q[w] = q; }
    __syncthreads();
    s = sh_s[0] + sh_s[1] + sh_s[2] + sh_s[3];
    q = sh_q[0] + sh_q[1] + sh_q[2] + sh_q[3];
    const float mu  = s * (1.f / 768.f);
    const float var = q * (1.f / 768.f) - mu * mu;
    const float inv = rsqrtf(var + LN_EPSF);
    y[tid]       = ((x0 - mu) * inv * g[tid]       + be[tid])       * scale;
    y[tid + 256] = ((x1 - mu) * inv * g[tid + 256] + be[tid + 256]) * scale;
    y[tid + 512] = ((x2 - mu) * inv * g[tid + 512] + be[tid + 512]) * scale;
}

// ---------------------------------------------------------------------------
// Kernel A: raw scores S = q @ k^T  (q pre-scaled), write S to attn region,
// track per-row running max & sum(exp) online. Block = (b,h, 16 q-rows).
// ---------------------------------------------------------------------------
__global__ __launch_bounds__(256) void attn_scores(
    const float* __restrict__ Qln, const float* __restrict__ Kln,
    float* __restrict__ attn, float* __restrict__ rmax, float* __restrict__ rsum)
{
    const int tid = threadIdx.x;
    const int mt = blockIdx.x % (MM / 16);
    const int bh = blockIdx.x / (MM / 16);
    const int h = bh % HH, b = bh / HH;

    __shared__ float qs[16][68];
    __shared__ float ksT[64][132];   // [k][n], padded

    {   // load Q tile 16x64
        const int m = tid >> 4, k4 = (tid & 15) << 2;
        *(float4*)&qs[m][k4] =
            *(const float4*)(Qln + ((size_t)(b * MM + mt * 16 + m)) * CC + h * DD + k4);
    }

    const int ty = tid >> 5;          // 0..7  -> rows m0,m1
    const int tx = tid & 31;          // 0..31 -> n = tx*4
    const int m0 = ty * 2, m1 = m0 + 1;

    float rm[2]  = {-1e30f, -1e30f};
    float rsv[2] = {0.f, 0.f};

    float* a0 = attn + ((size_t)(bh * MM + mt * 16 + m0)) * NN;
    float* a1 = attn + ((size_t)(bh * MM + mt * 16 + m1)) * NN;

    for (int n0 = 0; n0 < NN; n0 += 128) {
        __syncthreads();
        {   // stage K chunk transposed: ksT[k][n]
            const int kq = (tid & 15) << 2;
#pragma unroll
            for (int p = 0; p < 8; ++p) {
                const int n = (tid >> 4) + p * 16;
                float4 kv = *(const float4*)(Kln + ((size_t)(b * NN + n0 + n)) * CC + h * DD + kq);
                ksT[kq + 0][n] = kv.x; ksT[kq + 1][n] = kv.y;
                ksT[kq + 2][n] = kv.z; ksT[kq + 3][n] = kv.w;
            }
        }
        __syncthreads();

        float acc[2][4] = {{0, 0, 0, 0}, {0, 0, 0, 0}};
#pragma unroll
        for (int k4 = 0; k4 < 64; k4 += 4) {
            float4 qa = *(const float4*)&qs[m0][k4];
            float4 qb = *(const float4*)&qs[m1][k4];
            float qav[4] = {qa.x, qa.y, qa.z, qa.w};
            float qbv[4] = {qb.x, qb.y, qb.z, qb.w};
#pragma unroll
            for (int j = 0; j < 4; ++j) {
                float4 kv = *(const float4*)&ksT[k4 + j][tx * 4];
                acc[0][0] = fmaf(qav[j], kv.x, acc[0][0]);
                acc[0][1] = fmaf(qav[j], kv.y, acc[0][1]);
                acc[0][2] = fmaf(qav[j], kv.z, acc[0][2]);
                acc[0][3] = fmaf(qav[j], kv.w, acc[0][3]);
                acc[1][0] = fmaf(qbv[j], kv.x, acc[1][0]);
                acc[1][1] = fmaf(qbv[j], kv.y, acc[1][1]);
                acc[1][2] = fmaf(qbv[j], kv.z, acc[1][2]);
                acc[1][3] = fmaf(qbv[j], kv.w, acc[1][3]);
            }
        }
        *(float4*)(a0 + n0 + tx * 4) = make_float4(acc[0][0], acc[0][1], acc[0][2], acc[0][3]);
        *(float4*)(a1 + n0 + tx * 4) = make_float4(acc[1][0], acc[1][1], acc[1][2], acc[1][3]);

#pragma unroll
        for (int i = 0; i < 2; ++i) {
            float cmax = fmaxf(fmaxf(acc[i][0], acc[i][1]), fmaxf(acc[i][2], acc[i][3]));
#pragma unroll
            for (int o = 16; o >= 1; o >>= 1)
                cmax = fmaxf(cmax, __shfl_xor(cmax, o, 32));
            const float nm = fmaxf(rm[i], cmax);
            float cs = __expf(acc[i][0] - nm) + __expf(acc[i][1] - nm)
                     + __expf(acc[i][2] - nm) + __expf(acc[i][3] - nm);
#pragma unroll
            for (int o = 16; o >= 1; o >>= 1)
                cs += __shfl_xor(cs, o, 32);
            rsv[i] = rsv[i] * __expf(rm[i] - nm) + cs;
            rm[i] = nm;
        }
    }
    if (tx == 0) {
        const int base = bh * MM + mt * 16;
        rmax[base + m0] = rm[0]; rsum[base + m0] = rsv[0];
        rmax[base + m1] = rm[1]; rsum[base + m1] = rsv[1];
    }
}

// ---------------------------------------------------------------------------
// Kernel B: p = exp(s-max)/sum (write back to attn), out = p @ V + residual.
// Block = (b,h, 16 q-rows), 128 threads.
// ---------------------------------------------------------------------------
__global__ __launch_bounds__(128) void attn_pv(
    float* __restrict__ attn, const float* __restrict__ V,
    const float* __restrict__ rmax, const float* __restrict__ rsum,
    const float* __restrict__ qtok, float* __restrict__ out0)
{
    const int tid = threadIdx.x;
    const int mt = blockIdx.x % (MM / 16);
    const int bh = blockIdx.x / (MM / 16);
    const int h = bh % HH, b = bh / HH;

    __shared__ float ps[16][68];
    __shared__ float vs[64][68];

    const int ty = tid >> 4;   // 0..7 -> rows m0,m1
    const int tx = tid & 15;   // 0..15 -> d or n = tx*4
    const int m0 = ty * 2, m1 = m0 + 1;
    const int base = bh * MM + mt * 16;

    const float rm0 = rmax[base + m0], is0 = 1.f / rsum[base + m0];
    const float rm1 = rmax[base + m1], is1 = 1.f / rsum[base + m1];

    float* a0 = attn + (size_t)(base + m0) * NN;
    float* a1 = attn + (size_t)(base + m1) * NN;

    float acc[2][4] = {{0, 0, 0, 0}, {0, 0, 0, 0}};

    for (int n0 = 0; n0 < NN; n0 += 64) {
        __syncthreads();
#pragma unroll
        for (int p = 0; p < 8; ++p) {   // V chunk 64x64
            const int n = (tid >> 4) + p * 8;
            *(float4*)&vs[n][tx * 4] =
                *(const float4*)(V + ((size_t)(b * NN + n0 + n)) * CC + h * DD + tx * 4);
        }
        float4 s0 = *(const float4*)(a0 + n0 + tx * 4);
        float4 s1 = *(const float4*)(a1 + n0 + tx * 4);
        float4 p0 = make_float4(__expf(s0.x - rm0) * is0, __expf(s0.y - rm0) * is0,
                                __expf(s0.z - rm0) * is0, __expf(s0.w - rm0) * is0);
        float4 p1 = make_float4(__expf(s1.x - rm1) * is1, __expf(s1.y - rm1) * is1,
                                __expf(s1.z - rm1) * is1, __expf(s1.w - rm1) * is1);
        *(float4*)(a0 + n0 + tx * 4) = p0;
        *(float4*)(a1 + n0 + tx * 4) = p1;
        *(float4*)&ps[m0][tx * 4] = p0;
        *(float4*)&ps[m1][tx * 4] = p1;
        __syncthreads();
#pragma unroll
        for (int nk = 0; nk < 64; nk += 4) {
            float4 pa = *(const float4*)&ps[m0][nk];
            float4 pb = *(const float4*)&ps[m1][nk];
            float pav[4] = {pa.x, pa.y, pa.z, pa.w};
            float pbv[4] = {pb.x, pb.y, pb.z, pb.w};
#pragma unroll
            for (int j = 0; j < 4; ++j) {
                float4 vv = *(const float4*)&vs[nk + j][tx * 4];
                acc[0][0] = fmaf(pav[j], vv.x, acc[0][0]);
                acc[0][1] = fmaf(pav[j], vv.y, acc[0][1]);
                acc[0][2] = fmaf(pav[j], vv.z, acc[0][2]);
                acc[0][3] = fmaf(pav[j], vv.w, acc[0][3]);
                acc[1][0] = fmaf(pbv[j], vv.x, acc[1][0]);
                acc[1][1] = fmaf(pbv[j], vv.y, acc[1][1]);
                acc[1][2] = fmaf(pbv[j], vv.z, acc[1][2]);
                acc[1][3] = fmaf(pbv[j], vv.w, acc[1][3]);
            }
        }
    }
    const size_t o0 = ((size_t)(b * MM + mt * 16 + m0)) * CC + h * DD + tx * 4;
    const size_t o1 = ((size_t)(b * MM + mt * 16 + m1)) * CC + h * DD + tx * 4;
    float4 q0 = *(const float4*)(qtok + o0);
    float4 q1 = *(const float4*)(qtok + o1);
    *(float4*)(out0 + o0) = make_float4(q0.x + acc[0][0], q0.y + acc[0][1],
                                        q0.z + acc[0][2], q0.w + acc[0][3]);
    *(float4*)(out0 + o1) = make_float4(q1.x + acc[1][0], q1.y + acc[1][1],
                                        q1.z + acc[1][2], q1.w + acc[1][3]);
}

extern "C" void kernel_launch(void* const* d_in, const int* in_sizes, int n_in,
                              void* d_out, int out_size, void* d_ws, size_t ws_size,
                              hipStream_t stream) {
    (void)in_sizes; (void)n_in; (void)out_size; (void)ws_size;
    const float* input_tokens = (const float*)d_in[0];
    const float* query_tokens = (const float*)d_in[1];
    const float* Wq   = (const float*)d_in[2];
    const float* bq   = (const float*)d_in[3];
    const float* Wk   = (const float*)d_in[4];
    const float* bk   = (const float*)d_in[5];
    const float* Wv   = (const float*)d_in[6];
    const float* bv   = (const float*)d_in[7];
    const float* gq   = (const float*)d_in[8];
    const float* bqln = (const float*)d_in[9];
    const float* gk   = (const float*)d_in[10];
    const float* bkln = (const float*)d_in[11];

    float* out0 = (float*)d_out;
    float* attn = out0 + (size_t)BB * MM * CC;

    float* ws    = (float*)d_ws;
    float* Vbuf  = ws;                                 // B*N*C
    float* Klin  = Vbuf + (size_t)BB * NN * CC;        // B*N*C
    float* Qlin  = Klin + (size_t)BB * NN * CC;        // B*M*C
    float* rmaxb = Qlin + (size_t)BB * MM * CC;        // B*H*M
    float* rsumb = rmaxb + (size_t)BB * HH * MM;       // B*H*M

    proj_gemm<<<dim3(BB * NN / 64, CC / 64), 256, 0, stream>>>(input_tokens, Wk, bk, Klin);
    proj_gemm<<<dim3(BB * NN / 64, CC / 64), 256, 0, stream>>>(input_tokens, Wv, bv, Vbuf);
    proj_gemm<<<dim3(BB * MM / 64, CC / 64), 256, 0, stream>>>(query_tokens, Wq, bq, Qlin);

    ln_rows<<<BB * NN, 256, 0, stream>>>(Klin, gk, bkln, 1.0f);
    ln_rows<<<BB * MM, 256, 0, stream>>>(Qlin, gq, bqln, SCALEF);

    attn_scores<<<BB * HH * (MM / 16), 256, 0, stream>>>(Qlin, Klin, attn, rmaxb, rsumb);
    attn_pv<<<BB * HH * (MM / 16), 128, 0, stream>>>(attn, Vbuf, rmaxb, rsumb, query_tokens, out0);
}

// Round 2
// 526.875 us; speedup vs baseline: 1.8385x; 1.8385x over previous
//
#include <hip/hip_runtime.h>
#include <math.h>

#define BB 4
#define NN 4096
#define MM 256
#define CC 768
#define HH 12
#define DD 64
#define SCALEF 0.125f
#define LN_EPSF 1e-5f

typedef __attribute__((ext_vector_type(8))) short short8;
typedef __attribute__((ext_vector_type(8))) unsigned short ushort8;
typedef __attribute__((ext_vector_type(4))) float f32x4;

// ---------------------------------------------------------------------------
// helpers
// ---------------------------------------------------------------------------
__device__ __forceinline__ unsigned short f2bf(float f) {
    union { float f; unsigned int u; } v; v.f = f;
    unsigned int u = v.u;
    u = (u + 0x7FFFu + ((u >> 16) & 1u)) >> 16;
    return (unsigned short)u;
}
__device__ __forceinline__ float bf2f(unsigned short h) {
    union { unsigned int u; float f; } v; v.u = ((unsigned int)h) << 16;
    return v.f;
}

__device__ __forceinline__ void gld_lds16(const unsigned short* g, unsigned short* l) {
    __builtin_amdgcn_global_load_lds(
        (const __attribute__((address_space(1))) void*)g,
        (__attribute__((address_space(3))) void*)l, 16, 0, 0);
}

// ---------------------------------------------------------------------------
// f32 -> bf16 (RNE), vectorized, grid-stride. n % 8 == 0.
// ---------------------------------------------------------------------------
__global__ __launch_bounds__(256) void conv_bf16(
    const float* __restrict__ x, unsigned short* __restrict__ y, long long n)
{
    long long i = ((long long)blockIdx.x * 256 + threadIdx.x) * 8;
    const long long stride = (long long)gridDim.x * 256 * 8;
    for (; i < n; i += stride) {
        float4 a = *(const float4*)(x + i);
        float4 b = *(const float4*)(x + i + 4);
        ushort8 o;
        o[0] = f2bf(a.x); o[1] = f2bf(a.y); o[2] = f2bf(a.z); o[3] = f2bf(a.w);
        o[4] = f2bf(b.x); o[5] = f2bf(b.y); o[6] = f2bf(b.z); o[7] = f2bf(b.w);
        *(ushort8*)(y + i) = o;
    }
}

// ---------------------------------------------------------------------------
// W[768][768] f32 -> out[768][1536] bf16 split: [c][k]=hi, [c][768+k]=lo
// ---------------------------------------------------------------------------
__global__ __launch_bounds__(256) void conv_w_split(
    const float* __restrict__ W, unsigned short* __restrict__ out)
{
    const int idx = blockIdx.x * 256 + threadIdx.x;   // c*768 + k
    const int c = idx / CC, k = idx % CC;
    const float w = W[idx];
    const unsigned short hi = f2bf(w);
    const unsigned short lo = f2bf(w - bf2f(hi));
    out[(size_t)c * 1536 + k] = hi;
    out[(size_t)c * 1536 + CC + k] = lo;
}

// ---------------------------------------------------------------------------
// bf16 MFMA GEMM: out[r][c] = sum_k A[r][k mod kmod] * B[c][k] + bias[c]
// 128x128 tile, BK=32, 256 thr (4 waves, 2x2 of 64x64), 16x16x32 MFMA,
// global_load_lds width-16 staging, double-buffered LDS (m97 structure).
// One dispatch covers K-proj (K=1536 split), Q-proj (K=1536), V-proj (K=768).
// ---------------------------------------------------------------------------
__global__ __launch_bounds__(256) void proj_gemm_mfma(
    const unsigned short* __restrict__ Xb,   // [16384][768] bf16 (input_tokens)
    const unsigned short* __restrict__ X2b,  // [1024][768]  bf16 (query_tokens)
    const unsigned short* __restrict__ Wkb2, // [768][1536]
    const unsigned short* __restrict__ Wqb2, // [768][1536]
    const unsigned short* __restrict__ Wvb,  // [768][768]
    const float* __restrict__ bk, const float* __restrict__ bq,
    const float* __restrict__ bv,
    float* __restrict__ Klin, float* __restrict__ Qlin, float* __restrict__ Vbuf)
{
    __shared__ unsigned short As[2][128 * 32];
    __shared__ unsigned short Bs[2][128 * 32];

    const int bid = blockIdx.x;
    const unsigned short* Ag; const unsigned short* Bg;
    const float* bias; float* out;
    int K, lda, ldb, sid;
    if (bid < 768) {            // K projection: X1 @ [Wk_hi|Wk_lo]
        sid = bid; Ag = Xb; Bg = Wkb2; bias = bk; out = Klin;
        K = 1536; lda = CC; ldb = 1536;
    } else if (bid < 816) {     // Q projection: X2 @ [Wq_hi|Wq_lo]
        sid = bid - 768; Ag = X2b; Bg = Wqb2; bias = bq; out = Qlin;
        K = 1536; lda = CC; ldb = 1536;
    } else {                    // V projection: X1 @ Wv
        sid = bid - 816; Ag = Xb; Bg = Wvb; bias = bv; out = Vbuf;
        K = CC; lda = CC; ldb = CC;
    }
    const int bm = sid / 6, bn = sid % 6;
    const int row0 = bm * 128, col0 = bn * 128;

    const int tid = threadIdx.x;
    const int w = tid >> 6, lane = tid & 63;
    const int wr = w >> 1, wc = w & 1;
    const int fr = lane & 15, kg = lane >> 4;

    f32x4 acc[4][4];
#pragma unroll
    for (int m = 0; m < 4; ++m)
#pragma unroll
        for (int n = 0; n < 4; ++n)
            acc[m][n] = (f32x4){0.f, 0.f, 0.f, 0.f};

    const int nk = K >> 5;   // K-steps of 32

    // ---- staging lambda (plain code, done twice) ----
#define STAGE(sel, kt)                                                          \
    do {                                                                        \
        const int kk = (kt) << 5;                                               \
        const int kka = (kk >= CC) ? kk - CC : kk;  /* A addressed mod 768 */   \
        _Pragma("unroll")                                                       \
        for (int i = 0; i < 2; ++i) {                                           \
            const int cbase = (i * 4 + w) * 64;                                 \
            const int c = cbase + lane;                                         \
            const int row = c >> 2, ks = (c & 3) << 3;                          \
            gld_lds16(Ag + (size_t)(row0 + row) * lda + kka + ks,               \
                      &As[sel][cbase * 8]);                                     \
            gld_lds16(Bg + (size_t)(col0 + row) * ldb + kk + ks,                \
                      &Bs[sel][cbase * 8]);                                     \
        }                                                                       \
    } while (0)

    STAGE(0, 0);
    int cur = 0;
    for (int kt = 0; kt < nk; ++kt) {
        __syncthreads();
        if (kt + 1 < nk) STAGE(cur ^ 1, kt + 1);
        const unsigned short* lA = As[cur];
        const unsigned short* lB = Bs[cur];
        short8 a[4], b[4];
#pragma unroll
        for (int m = 0; m < 4; ++m)
            a[m] = *(const short8*)(lA + (wr * 64 + m * 16 + fr) * 32 + kg * 8);
#pragma unroll
        for (int n = 0; n < 4; ++n)
            b[n] = *(const short8*)(lB + (wc * 64 + n * 16 + fr) * 32 + kg * 8);
#pragma unroll
        for (int m = 0; m < 4; ++m)
#pragma unroll
            for (int n = 0; n < 4; ++n)
                acc[m][n] = __builtin_amdgcn_mfma_f32_16x16x32_bf16(
                    a[m], b[n], acc[m][n], 0, 0, 0);
        cur ^= 1;
    }
#undef STAGE

    // epilogue: C/D layout col=lane&15, row=(lane>>4)*4+reg
    float bvv[4];
#pragma unroll
    for (int n = 0; n < 4; ++n)
        bvv[n] = bias[col0 + wc * 64 + n * 16 + fr];
#pragma unroll
    for (int m = 0; m < 4; ++m)
#pragma unroll
        for (int n = 0; n < 4; ++n) {
            const int col = col0 + wc * 64 + n * 16 + fr;
#pragma unroll
            for (int r = 0; r < 4; ++r) {
                const int row = row0 + wr * 64 + m * 16 + kg * 4 + r;
                out[(size_t)row * CC + col] = acc[m][n][r] + bvv[n];
            }
        }
}

// ---------------------------------------------------------------------------
// In-place LayerNorm over rows of 768; optional output scale (Q gets 1/sqrt(D))
// ---------------------------------------------------------------------------
__global__ __launch_bounds__(256) void ln_rows(
    float* __restrict__ Y, const float* __restrict__ g,
    const float* __restrict__ be, const float scale)
{
    const int row = blockIdx.x;
    float* y = Y + (size_t)row * CC;
    const int tid = threadIdx.x;
    float x0 = y[tid], x1 = y[tid + 256], x2 = y[tid + 512];
    float s = x0 + x1 + x2;
    float q = x0 * x0 + x1 * x1 + x2 * x2;
#pragma unroll
    for (int o = 32; o >= 1; o >>= 1) {
        s += __shfl_xor(s, o, 64);
        q += __shfl_xor(q, o, 64);
    }
    __shared__ float sh_s[4], sh_q[4];
    const int w = tid >> 6;
    if ((tid & 63) == 0) { sh_s[w] = s; sh_q[w] = q; }
    __syncthreads();
    s = sh_s[0] + sh_s[1] + sh_s[2] + sh_s[3];
    q = sh_q[0] + sh_q[1] + sh_q[2] + sh_q[3];
    const float mu  = s * (1.f / 768.f);
    const float var = q * (1.f / 768.f) - mu * mu;
    const float inv = rsqrtf(var + LN_EPSF);
    y[tid]       = ((x0 - mu) * inv * g[tid]       + be[tid])       * scale;
    y[tid + 256] = ((x1 - mu) * inv * g[tid + 256] + be[tid + 256]) * scale;
    y[tid + 512] = ((x2 - mu) * inv * g[tid + 512] + be[tid + 512]) * scale;
}

// ---------------------------------------------------------------------------
// Kernel A: raw scores S = q @ k^T  (q pre-scaled), write S to attn region,
// track per-row running max & sum(exp) online. Block = (b,h, 16 q-rows).
// ---------------------------------------------------------------------------
__global__ __launch_bounds__(256) void attn_scores(
    const float* __restrict__ Qln, const float* __restrict__ Kln,
    float* __restrict__ attn, float* __restrict__ rmax, float* __restrict__ rsum)
{
    const int tid = threadIdx.x;
    const int mt = blockIdx.x % (MM / 16);
    const int bh = blockIdx.x / (MM / 16);
    const int h = bh % HH, b = bh / HH;

    __shared__ float qs[16][68];
    __shared__ float ksT[64][132];   // [k][n], padded

    {   // load Q tile 16x64
        const int m = tid >> 4, k4 = (tid & 15) << 2;
        *(float4*)&qs[m][k4] =
            *(const float4*)(Qln + ((size_t)(b * MM + mt * 16 + m)) * CC + h * DD + k4);
    }

    const int ty = tid >> 5;          // 0..7  -> rows m0,m1
    const int tx = tid & 31;          // 0..31 -> n = tx*4
    const int m0 = ty * 2, m1 = m0 + 1;

    float rm[2]  = {-1e30f, -1e30f};
    float rsv[2] = {0.f, 0.f};

    float* a0 = attn + ((size_t)(bh * MM + mt * 16 + m0)) * NN;
    float* a1 = attn + ((size_t)(bh * MM + mt * 16 + m1)) * NN;

    for (int n0 = 0; n0 < NN; n0 += 128) {
        __syncthreads();
        {   // stage K chunk transposed: ksT[k][n]
            const int kq = (tid & 15) << 2;
#pragma unroll
            for (int p = 0; p < 8; ++p) {
                const int n = (tid >> 4) + p * 16;
                float4 kv = *(const float4*)(Kln + ((size_t)(b * NN + n0 + n)) * CC + h * DD + kq);
                ksT[kq + 0][n] = kv.x; ksT[kq + 1][n] = kv.y;
                ksT[kq + 2][n] = kv.z; ksT[kq + 3][n] = kv.w;
            }
        }
        __syncthreads();

        float acc[2][4] = {{0, 0, 0, 0}, {0, 0, 0, 0}};
#pragma unroll
        for (int k4 = 0; k4 < 64; k4 += 4) {
            float4 qa = *(const float4*)&qs[m0][k4];
            float4 qb = *(const float4*)&qs[m1][k4];
            float qav[4] = {qa.x, qa.y, qa.z, qa.w};
            float qbv[4] = {qb.x, qb.y, qb.z, qb.w};
#pragma unroll
            for (int j = 0; j < 4; ++j) {
                float4 kv = *(const float4*)&ksT[k4 + j][tx * 4];
                acc[0][0] = fmaf(qav[j], kv.x, acc[0][0]);
                acc[0][1] = fmaf(qav[j], kv.y, acc[0][1]);
                acc[0][2] = fmaf(qav[j], kv.z, acc[0][2]);
                acc[0][3] = fmaf(qav[j], kv.w, acc[0][3]);
                acc[1][0] = fmaf(qbv[j], kv.x, acc[1][0]);
                acc[1][1] = fmaf(qbv[j], kv.y, acc[1][1]);
                acc[1][2] = fmaf(qbv[j], kv.z, acc[1][2]);
                acc[1][3] = fmaf(qbv[j], kv.w, acc[1][3]);
            }
        }
        *(float4*)(a0 + n0 + tx * 4) = make_float4(acc[0][0], acc[0][1], acc[0][2], acc[0][3]);
        *(float4*)(a1 + n0 + tx * 4) = make_float4(acc[1][0], acc[1][1], acc[1][2], acc[1][3]);

#pragma unroll
        for (int i = 0; i < 2; ++i) {
            float cmax = fmaxf(fmaxf(acc[i][0], acc[i][1]), fmaxf(acc[i][2], acc[i][3]));
#pragma unroll
            for (int o = 16; o >= 1; o >>= 1)
                cmax = fmaxf(cmax, __shfl_xor(cmax, o, 32));
            const float nm = fmaxf(rm[i], cmax);
            float cs = __expf(acc[i][0] - nm) + __expf(acc[i][1] - nm)
                     + __expf(acc[i][2] - nm) + __expf(acc[i][3] - nm);
#pragma unroll
            for (int o = 16; o >= 1; o >>= 1)
                cs += __shfl_xor(cs, o, 32);
            rsv[i] = rsv[i] * __expf(rm[i] - nm) + cs;
            rm[i] = nm;
        }
    }
    if (tx == 0) {
        const int base = bh * MM + mt * 16;
        rmax[base + m0] = rm[0]; rsum[base + m0] = rsv[0];
        rmax[base + m1] = rm[1]; rsum[base + m1] = rsv[1];
    }
}

// ---------------------------------------------------------------------------
// Kernel B: p = exp(s-max)/sum (write back to attn), out = p @ V + residual.
// Block = (b,h, 16 q-rows), 128 threads.
// ---------------------------------------------------------------------------
__global__ __launch_bounds__(128) void attn_pv(
    float* __restrict__ attn, const float* __restrict__ V,
    const float* __restrict__ rmax, const float* __restrict__ rsum,
    const float* __restrict__ qtok, float* __restrict__ out0)
{
    const int tid = threadIdx.x;
    const int mt = blockIdx.x % (MM / 16);
    const int bh = blockIdx.x / (MM / 16);
    const int h = bh % HH, b = bh / HH;

    __shared__ float ps[16][68];
    __shared__ float vs[64][68];

    const int ty = tid >> 4;   // 0..7 -> rows m0,m1
    const int tx = tid & 15;   // 0..15 -> d or n = tx*4
    const int m0 = ty * 2, m1 = m0 + 1;
    const int base = bh * MM + mt * 16;

    const float rm0 = rmax[base + m0], is0 = 1.f / rsum[base + m0];
    const float rm1 = rmax[base + m1], is1 = 1.f / rsum[base + m1];

    float* a0 = attn + (size_t)(base + m0) * NN;
    float* a1 = attn + (size_t)(base + m1) * NN;

    float acc[2][4] = {{0, 0, 0, 0}, {0, 0, 0, 0}};

    for (int n0 = 0; n0 < NN; n0 += 64) {
        __syncthreads();
#pragma unroll
        for (int p = 0; p < 8; ++p) {   // V chunk 64x64
            const int n = (tid >> 4) + p * 8;
            *(float4*)&vs[n][tx * 4] =
                *(const float4*)(V + ((size_t)(b * NN + n0 + n)) * CC + h * DD + tx * 4);
        }
        float4 s0 = *(const float4*)(a0 + n0 + tx * 4);
        float4 s1 = *(const float4*)(a1 + n0 + tx * 4);
        float4 p0 = make_float4(__expf(s0.x - rm0) * is0, __expf(s0.y - rm0) * is0,
                                __expf(s0.z - rm0) * is0, __expf(s0.w - rm0) * is0);
        float4 p1 = make_float4(__expf(s1.x - rm1) * is1, __expf(s1.y - rm1) * is1,
                                __expf(s1.z - rm1) * is1, __expf(s1.w - rm1) * is1);
        *(float4*)(a0 + n0 + tx * 4) = p0;
        *(float4*)(a1 + n0 + tx * 4) = p1;
        *(float4*)&ps[m0][tx * 4] = p0;
        *(float4*)&ps[m1][tx * 4] = p1;
        __syncthreads();
#pragma unroll
        for (int nk = 0; nk < 64; nk += 4) {
            float4 pa = *(const float4*)&ps[m0][nk];
            float4 pb = *(const float4*)&ps[m1][nk];
            float pav[4] = {pa.x, pa.y, pa.z, pa.w};
            float pbv[4] = {pb.x, pb.y, pb.z, pb.w};
#pragma unroll
            for (int j = 0; j < 4; ++j) {
                float4 vv = *(const float4*)&vs[nk + j][tx * 4];
                acc[0][0] = fmaf(pav[j], vv.x, acc[0][0]);
                acc[0][1] = fmaf(pav[j], vv.y, acc[0][1]);
                acc[0][2] = fmaf(pav[j], vv.z, acc[0][2]);
                acc[0][3] = fmaf(pav[j], vv.w, acc[0][3]);
                acc[1][0] = fmaf(pbv[j], vv.x, acc[1][0]);
                acc[1][1] = fmaf(pbv[j], vv.y, acc[1][1]);
                acc[1][2] = fmaf(pbv[j], vv.z, acc[1][2]);
                acc[1][3] = fmaf(pbv[j], vv.w, acc[1][3]);
            }
        }
    }
    const size_t o0 = ((size_t)(b * MM + mt * 16 + m0)) * CC + h * DD + tx * 4;
    const size_t o1 = ((size_t)(b * MM + mt * 16 + m1)) * CC + h * DD + tx * 4;
    float4 q0 = *(const float4*)(qtok + o0);
    float4 q1 = *(const float4*)(qtok + o1);
    *(float4*)(out0 + o0) = make_float4(q0.x + acc[0][0], q0.y + acc[0][1],
                                        q0.z + acc[0][2], q0.w + acc[0][3]);
    *(float4*)(out0 + o1) = make_float4(q1.x + acc[1][0], q1.y + acc[1][1],
                                        q1.z + acc[1][2], q1.w + acc[1][3]);
}

extern "C" void kernel_launch(void* const* d_in, const int* in_sizes, int n_in,
                              void* d_out, int out_size, void* d_ws, size_t ws_size,
                              hipStream_t stream) {
    (void)in_sizes; (void)n_in; (void)out_size; (void)ws_size;
    const float* input_tokens = (const float*)d_in[0];
    const float* query_tokens = (const float*)d_in[1];
    const float* Wq   = (const float*)d_in[2];
    const float* bq   = (const float*)d_in[3];
    const float* Wk   = (const float*)d_in[4];
    const float* bk   = (const float*)d_in[5];
    const float* Wv   = (const float*)d_in[6];
    const float* bv   = (const float*)d_in[7];
    const float* gq   = (const float*)d_in[8];
    const float* bqln = (const float*)d_in[9];
    const float* gk   = (const float*)d_in[10];
    const float* bkln = (const float*)d_in[11];

    float* out0 = (float*)d_out;
    float* attn = out0 + (size_t)BB * MM * CC;

    float* ws    = (float*)d_ws;
    float* Klin  = ws;                                  // 12,582,912 f32
    float* Vbuf  = Klin + (size_t)BB * NN * CC;         // 12,582,912 f32
    float* Qlin  = Vbuf + (size_t)BB * NN * CC;         //    786,432 f32
    float* rmaxb = Qlin + (size_t)BB * MM * CC;         //     12,288 f32
    float* rsumb = rmaxb + (size_t)BB * HH * MM;        //     12,288 f32
    unsigned short* Xb   = (unsigned short*)(rsumb + (size_t)BB * HH * MM);
    unsigned short* X2b  = Xb   + (size_t)BB * NN * CC; // 16384x768 bf16
    unsigned short* Wkb2 = X2b  + (size_t)BB * MM * CC; // 1024x768 bf16
    unsigned short* Wqb2 = Wkb2 + (size_t)CC * 1536;    // 768x1536
    unsigned short* Wvb  = Wqb2 + (size_t)CC * 1536;    // 768x1536
                                                        // Wvb: 768x768

    // --- convert inputs/weights to bf16 ---
    conv_bf16<<<2048, 256, 0, stream>>>(input_tokens, Xb, (long long)BB * NN * CC);
    conv_bf16<<<384, 256, 0, stream>>>(query_tokens, X2b, (long long)BB * MM * CC);
    conv_bf16<<<288, 256, 0, stream>>>(Wv, Wvb, (long long)CC * CC);
    conv_w_split<<<(CC * CC) / 256, 256, 0, stream>>>(Wk, Wkb2);
    conv_w_split<<<(CC * CC) / 256, 256, 0, stream>>>(Wq, Wqb2);

    // --- all three projections in one MFMA dispatch ---
    proj_gemm_mfma<<<1584, 256, 0, stream>>>(Xb, X2b, Wkb2, Wqb2, Wvb,
                                             bk, bq, bv, Klin, Qlin, Vbuf);

    ln_rows<<<BB * NN, 256, 0, stream>>>(Klin, gk, bkln, 1.0f);
    ln_rows<<<BB * MM, 256, 0, stream>>>(Qlin, gq, bqln, SCALEF);

    attn_scores<<<BB * HH * (MM / 16), 256, 0, stream>>>(Qlin, Klin, attn, rmaxb, rsumb);
    attn_pv<<<BB * HH * (MM / 16), 128, 0, stream>>>(attn, Vbuf, rmaxb, rsumb, query_tokens, out0);
}

// Round 3
// 306.158 us; speedup vs baseline: 3.1639x; 1.7209x over previous
//
#include <hip/hip_runtime.h>
#include <math.h>

#define BB 4
#define NN 4096
#define MM 256
#define CC 768
#define HH 12
#define DD 64
#define SCALEF 0.125f
#define LN_EPSF 1e-5f

typedef __attribute__((ext_vector_type(8))) short short8;
typedef __attribute__((ext_vector_type(8))) unsigned short ushort8;
typedef __attribute__((ext_vector_type(4))) float f32x4;
typedef __attribute__((ext_vector_type(16))) float f32x16;
typedef __attribute__((ext_vector_type(8))) _Float16 f16x8;
typedef __attribute__((ext_vector_type(4))) _Float16 f16x4;

// ---------------------------------------------------------------------------
// helpers
// ---------------------------------------------------------------------------
__device__ __forceinline__ unsigned short f2bf(float f) {
    union { float f; unsigned int u; } v; v.f = f;
    unsigned int u = v.u;
    u = (u + 0x7FFFu + ((u >> 16) & 1u)) >> 16;
    return (unsigned short)u;
}
__device__ __forceinline__ float bf2f(unsigned short h) {
    union { unsigned int u; float f; } v; v.u = ((unsigned int)h) << 16;
    return v.f;
}

__device__ __forceinline__ void gld_lds16(const unsigned short* g, unsigned short* l) {
    __builtin_amdgcn_global_load_lds(
        (const __attribute__((address_space(1))) void*)g,
        (__attribute__((address_space(3))) void*)l, 16, 0, 0);
}
__device__ __forceinline__ void gldh(const _Float16* g, _Float16* l) {
    __builtin_amdgcn_global_load_lds(
        (const __attribute__((address_space(1))) void*)g,
        (__attribute__((address_space(3))) void*)l, 16, 0, 0);
}

// ---------------------------------------------------------------------------
// f32 -> bf16 (RNE), vectorized, grid-stride. n % 8 == 0.
// ---------------------------------------------------------------------------
__global__ __launch_bounds__(256) void conv_bf16(
    const float* __restrict__ x, unsigned short* __restrict__ y, long long n)
{
    long long i = ((long long)blockIdx.x * 256 + threadIdx.x) * 8;
    const long long stride = (long long)gridDim.x * 256 * 8;
    for (; i < n; i += stride) {
        float4 a = *(const float4*)(x + i);
        float4 b = *(const float4*)(x + i + 4);
        ushort8 o;
        o[0] = f2bf(a.x); o[1] = f2bf(a.y); o[2] = f2bf(a.z); o[3] = f2bf(a.w);
        o[4] = f2bf(b.x); o[5] = f2bf(b.y); o[6] = f2bf(b.z); o[7] = f2bf(b.w);
        *(ushort8*)(y + i) = o;
    }
}

// ---------------------------------------------------------------------------
// W[768][768] f32 -> out[768][1536] bf16 split: [c][k]=hi, [c][768+k]=lo
// ---------------------------------------------------------------------------
__global__ __launch_bounds__(256) void conv_w_split(
    const float* __restrict__ W, unsigned short* __restrict__ out)
{
    const int idx = blockIdx.x * 256 + threadIdx.x;   // c*768 + k
    const int c = idx / CC, k = idx % CC;
    const float w = W[idx];
    const unsigned short hi = f2bf(w);
    const unsigned short lo = f2bf(w - bf2f(hi));
    out[(size_t)c * 1536 + k] = hi;
    out[(size_t)c * 1536 + CC + k] = lo;
}

// ---------------------------------------------------------------------------
// bf16 MFMA GEMM (m97 structure). K-proj (K=1536 split), Q-proj (K=1536),
// V-proj (K=768, epilogue writes fp16 V TRANSPOSED [b*H+h][d][token]).
// ---------------------------------------------------------------------------
__global__ __launch_bounds__(256) void proj_gemm_mfma(
    const unsigned short* __restrict__ Xb,   // [16384][768] bf16
    const unsigned short* __restrict__ X2b,  // [1024][768]  bf16
    const unsigned short* __restrict__ Wkb2, // [768][1536]
    const unsigned short* __restrict__ Wqb2, // [768][1536]
    const unsigned short* __restrict__ Wvb,  // [768][768]
    const float* __restrict__ bk, const float* __restrict__ bq,
    const float* __restrict__ bv,
    float* __restrict__ Klin, float* __restrict__ Qlin,
    _Float16* __restrict__ Vth)              // [48][64][4096] fp16
{
    __shared__ unsigned short As[2][128 * 32];
    __shared__ unsigned short Bs[2][128 * 32];

    const int bid = blockIdx.x;
    const unsigned short* Ag; const unsigned short* Bg;
    const float* bias; float* out = nullptr;
    int K, lda, ldb, sid;
    bool isV = false;
    if (bid < 768) {            // K projection
        sid = bid; Ag = Xb; Bg = Wkb2; bias = bk; out = Klin;
        K = 1536; lda = CC; ldb = 1536;
    } else if (bid < 816) {     // Q projection
        sid = bid - 768; Ag = X2b; Bg = Wqb2; bias = bq; out = Qlin;
        K = 1536; lda = CC; ldb = 1536;
    } else {                    // V projection
        sid = bid - 816; Ag = Xb; Bg = Wvb; bias = bv; isV = true;
        K = CC; lda = CC; ldb = CC;
    }
    const int bm = sid / 6, bn = sid % 6;
    const int row0 = bm * 128, col0 = bn * 128;

    const int tid = threadIdx.x;
    const int w = tid >> 6, lane = tid & 63;
    const int wr = w >> 1, wc = w & 1;
    const int fr = lane & 15, kg = lane >> 4;

    f32x4 acc[4][4];
#pragma unroll
    for (int m = 0; m < 4; ++m)
#pragma unroll
        for (int n = 0; n < 4; ++n)
            acc[m][n] = (f32x4){0.f, 0.f, 0.f, 0.f};

    const int nk = K >> 5;   // K-steps of 32

#define STAGE(sel, kt)                                                          \
    do {                                                                        \
        const int kk = (kt) << 5;                                               \
        const int kka = (kk >= CC) ? kk - CC : kk;  /* A addressed mod 768 */   \
        _Pragma("unroll")                                                       \
        for (int i = 0; i < 2; ++i) {                                           \
            const int cbase = (i * 4 + w) * 64;                                 \
            const int c = cbase + lane;                                         \
            const int row = c >> 2, ks = (c & 3) << 3;                          \
            gld_lds16(Ag + (size_t)(row0 + row) * lda + kka + ks,               \
                      &As[sel][cbase * 8]);                                     \
            gld_lds16(Bg + (size_t)(col0 + row) * ldb + kk + ks,                \
                      &Bs[sel][cbase * 8]);                                     \
        }                                                                       \
    } while (0)

    STAGE(0, 0);
    int cur = 0;
    for (int kt = 0; kt < nk; ++kt) {
        __syncthreads();
        if (kt + 1 < nk) STAGE(cur ^ 1, kt + 1);
        const unsigned short* lA = As[cur];
        const unsigned short* lB = Bs[cur];
        short8 a[4], b[4];
#pragma unroll
        for (int m = 0; m < 4; ++m)
            a[m] = *(const short8*)(lA + (wr * 64 + m * 16 + fr) * 32 + kg * 8);
#pragma unroll
        for (int n = 0; n < 4; ++n)
            b[n] = *(const short8*)(lB + (wc * 64 + n * 16 + fr) * 32 + kg * 8);
#pragma unroll
        for (int m = 0; m < 4; ++m)
#pragma unroll
            for (int n = 0; n < 4; ++n)
                acc[m][n] = __builtin_amdgcn_mfma_f32_16x16x32_bf16(
                    a[m], b[n], acc[m][n], 0, 0, 0);
        cur ^= 1;
    }
#undef STAGE

    if (!isV) {
        // C/D layout col=lane&15, row=(lane>>4)*4+reg
        float bvv[4];
#pragma unroll
        for (int n = 0; n < 4; ++n)
            bvv[n] = bias[col0 + wc * 64 + n * 16 + fr];
#pragma unroll
        for (int m = 0; m < 4; ++m)
#pragma unroll
            for (int n = 0; n < 4; ++n) {
                const int col = col0 + wc * 64 + n * 16 + fr;
#pragma unroll
                for (int r = 0; r < 4; ++r) {
                    const int row = row0 + wr * 64 + m * 16 + kg * 4 + r;
                    out[(size_t)row * CC + col] = acc[m][n][r] + bvv[n];
                }
            }
    } else {
        // transposed fp16 store: Vth[(b*12 + h)*64 + d][token]
        const int b = row0 >> 12;
        const int rb = row0 & 4095;
#pragma unroll
        for (int n = 0; n < 4; ++n) {
            const int cg = col0 + wc * 64 + n * 16 + fr;
            const int hh = cg >> 6, d = cg & 63;
            const float bb = bias[cg];
            _Float16* vrow = Vth + ((size_t)((b * HH + hh) * DD + d)) * NN + rb + wr * 64;
#pragma unroll
            for (int m = 0; m < 4; ++m) {
                f16x4 v4;
#pragma unroll
                for (int r = 0; r < 4; ++r)
                    v4[r] = (_Float16)(acc[m][n][r] + bb);
                *(f16x4*)(vrow + m * 16 + kg * 4) = v4;
            }
        }
    }
}

// ---------------------------------------------------------------------------
// LayerNorm over rows of 768, fp16 output (scale folded; Q gets 1/sqrt(D))
// ---------------------------------------------------------------------------
__global__ __launch_bounds__(256) void ln_rows_f16(
    const float* __restrict__ Y, _Float16* __restrict__ outh,
    const float* __restrict__ g, const float* __restrict__ be, const float scale)
{
    const int row = blockIdx.x;
    const float* y = Y + (size_t)row * CC;
    const int tid = threadIdx.x;
    float x0 = y[tid], x1 = y[tid + 256], x2 = y[tid + 512];
    float s = x0 + x1 + x2;
    float q = x0 * x0 + x1 * x1 + x2 * x2;
#pragma unroll
    for (int o = 32; o >= 1; o >>= 1) {
        s += __shfl_xor(s, o, 64);
        q += __shfl_xor(q, o, 64);
    }
    __shared__ float sh_s[4], sh_q[4];
    const int w = tid >> 6;
    if ((tid & 63) == 0) { sh_s[w] = s; sh_q[w] = q; }
    __syncthreads();
    s = sh_s[0] + sh_s[1] + sh_s[2] + sh_s[3];
    q = sh_q[0] + sh_q[1] + sh_q[2] + sh_q[3];
    const float mu  = s * (1.f / 768.f);
    const float var = q * (1.f / 768.f) - mu * mu;
    const float inv = rsqrtf(var + LN_EPSF);
    _Float16* o = outh + (size_t)row * CC;
    o[tid]       = (_Float16)(((x0 - mu) * inv * g[tid]       + be[tid])       * scale);
    o[tid + 256] = (_Float16)(((x1 - mu) * inv * g[tid + 256] + be[tid + 256]) * scale);
    o[tid + 512] = (_Float16)(((x2 - mu) * inv * g[tid + 512] + be[tid + 512]) * scale);
}

// ---------------------------------------------------------------------------
// Fused flash attention: per (b,h,32 q-rows). Pass1: S=mfma(K,Q) online
// max/sum. Pass2: recompute S, write normalized P (f32) once, PV via MFMA.
// 4 waves, wave w owns n-tile w (32 n) of each 128-n chunk. XOR-swizzled LDS.
// ---------------------------------------------------------------------------
__global__ __launch_bounds__(256, 2) void fused_attn(
    const _Float16* __restrict__ Qh,   // [B][256][768] LN'd, *SCALE
    const _Float16* __restrict__ Kh,   // [B][4096][768] LN'd
    const _Float16* __restrict__ Vt,   // [B*H][64][4096]
    const float* __restrict__ qtok,
    float* __restrict__ attn, float* __restrict__ out0)
{
    __shared__ __align__(16) unsigned char smem[46080];
    _Float16* Kl = (_Float16*)smem;                    // [128][64] 16KB
    _Float16* Vl = (_Float16*)(smem + 16384);          // [64][128] 16KB
    _Float16* Ql = (_Float16*)(smem + 32768);          // [32][64]   4KB
    _Float16* Pl = (_Float16*)(smem + 36864);          // [32][128]  8KB
    float (*red)[32][2] = (float(*)[32][2])(smem + 45056);  // 1KB
    float* rbuf = (float*)smem;                        // epilogue 32KB

    const int tid = threadIdx.x;
    const int w = tid >> 6, lane = tid & 63;
    const int l5 = lane >> 5, lm = lane & 31;
    const int mt = blockIdx.x & 7;
    const int bh = blockIdx.x >> 3;
    const int h = bh % HH, b = bh / HH;
    const int qr0 = mt * 32;

#define STAGEK(c0)                                                              \
    _Pragma("unroll")                                                           \
    for (int i = 0; i < 4; ++i) {                                               \
        const int L = i * 256 + tid;                                            \
        const int n = L >> 3, pos = L & 7;                                      \
        gldh(Kh + (size_t)(b * NN + (c0) + n) * CC + h * DD + ((pos ^ (n & 7)) << 3), \
             &Kl[(i * 256 + w * 64) * 8]);                                      \
    }
#define STAGEV(c0)                                                              \
    _Pragma("unroll")                                                           \
    for (int i = 0; i < 4; ++i) {                                               \
        const int L = i * 256 + tid;                                            \
        const int d = L >> 4, pos = L & 15;                                     \
        const int blk = (pos & 8) | ((pos & 7) ^ (d & 7));                      \
        gldh(Vt + (size_t)(bh * DD + d) * NN + (c0) + blk * 8,                  \
             &Vl[(i * 256 + w * 64) * 8]);                                      \
    }

    {   // stage Q tile (32 rows x 64 d), swizzled
        const int n = tid >> 3, pos = tid & 7;
        gldh(Qh + (size_t)(b * MM + qr0 + n) * CC + h * DD + ((pos ^ (n & 7)) << 3),
             &Ql[(w * 64) * 8]);
    }
    __syncthreads();
    f16x8 qf[4];
#pragma unroll
    for (int ks = 0; ks < 4; ++ks)
        qf[ks] = *(const f16x8*)&Ql[lm * 64 + (((ks * 2 + l5) ^ (lm & 7)) << 3)];

    const int nl = w * 32 + lm;      // this lane's K row within chunk (A operand)

    // ---------------- pass 1: stats ----------------
    float mrun = -1e30f, srun = 0.f;
    for (int c = 0; c < 32; ++c) {
        __syncthreads();
        STAGEK(c * 128);
        __syncthreads();
        f32x16 s;
#pragma unroll
        for (int r = 0; r < 16; ++r) s[r] = 0.f;
#pragma unroll
        for (int ks = 0; ks < 4; ++ks) {
            f16x8 kf = *(const f16x8*)&Kl[nl * 64 + (((ks * 2 + l5) ^ (nl & 7)) << 3)];
            s = __builtin_amdgcn_mfma_f32_32x32x16_f16(kf, qf[ks], s, 0, 0, 0);
        }
        float cmax = s[0];
#pragma unroll
        for (int r = 1; r < 16; ++r) cmax = fmaxf(cmax, s[r]);
        cmax = fmaxf(cmax, __shfl_xor(cmax, 32, 64));
        const float nm = fmaxf(mrun, cmax);
        float cs = 0.f;
#pragma unroll
        for (int r = 0; r < 16; ++r) cs += __expf(s[r] - nm);
        cs += __shfl_xor(cs, 32, 64);
        srun = srun * __expf(mrun - nm) + cs;
        mrun = nm;
    }
    // merge stats across waves
    if (lane < 32) { red[w][lane][0] = mrun; red[w][lane][1] = srun; }
    __syncthreads();
    float M = -1e30f;
#pragma unroll
    for (int ww = 0; ww < 4; ++ww) M = fmaxf(M, red[ww][lm][0]);
    float S = 0.f;
#pragma unroll
    for (int ww = 0; ww < 4; ++ww) S += red[ww][lm][1] * __expf(red[ww][lm][0] - M);
    const float invS = 1.f / S;

    // ---------------- pass 2: P write + PV ----------------
    f32x16 oacc[2];
#pragma unroll
    for (int dt = 0; dt < 2; ++dt)
#pragma unroll
        for (int r = 0; r < 16; ++r) oacc[dt][r] = 0.f;

    float* attnRow = attn + ((size_t)(bh * MM + qr0 + lm)) * NN;

    for (int c = 0; c < 32; ++c) {
        __syncthreads();
        STAGEK(c * 128);
        STAGEV(c * 128);
        __syncthreads();
        f32x16 s;
#pragma unroll
        for (int r = 0; r < 16; ++r) s[r] = 0.f;
#pragma unroll
        for (int ks = 0; ks < 4; ++ks) {
            f16x8 kf = *(const f16x8*)&Kl[nl * 64 + (((ks * 2 + l5) ^ (nl & 7)) << 3)];
            s = __builtin_amdgcn_mfma_f32_32x32x16_f16(kf, qf[ks], s, 0, 0, 0);
        }
        // normalized P: global write (f32) + LDS write (f16, swizzled)
#pragma unroll
        for (int q = 0; q < 4; ++q) {
            float4 pw;
            f16x4 ph;
#pragma unroll
            for (int r = 0; r < 4; ++r) {
                const float p = __expf(s[q * 4 + r] - M) * invS;
                ((float*)&pw)[r] = p;
                ph[r] = (_Float16)p;
            }
            *(float4*)(attnRow + c * 128 + w * 32 + q * 8 + l5 * 4) = pw;
            const int blk16 = w * 4 + q;
            const int pos = (blk16 & 8) | ((blk16 & 7) ^ (lm & 7));
            *(f16x4*)&Pl[lm * 128 + pos * 8 + l5 * 4] = ph;
        }
        // PV partial over this wave's n-tile (k = 2 steps of 16)
#pragma unroll
        for (int ks = 0; ks < 2; ++ks) {
            const int blk16 = w * 4 + ks * 2 + l5;
            const int posP = (blk16 & 8) | ((blk16 & 7) ^ (lm & 7));
            f16x8 pf = *(const f16x8*)&Pl[lm * 128 + posP * 8];
#pragma unroll
            for (int dt = 0; dt < 2; ++dt) {
                const int d = dt * 32 + lm;
                const int posV = (blk16 & 8) | ((blk16 & 7) ^ (d & 7));
                f16x8 vf = *(const f16x8*)&Vl[d * 128 + posV * 8];
                oacc[dt] = __builtin_amdgcn_mfma_f32_32x32x16_f16(pf, vf, oacc[dt], 0, 0, 0);
            }
        }
    }

    // ---------------- epilogue: cross-wave reduce + residual ----------------
    __syncthreads();
#pragma unroll
    for (int dt = 0; dt < 2; ++dt)
#pragma unroll
        for (int r = 0; r < 16; ++r) {
            const int mrow = (r & 3) + 8 * (r >> 2) + 4 * l5;
            rbuf[w * 2048 + mrow * 64 + dt * 32 + lm] = oacc[dt][r];
        }
    __syncthreads();
    {
        const int m = tid >> 3, d0 = (tid & 7) * 8;
        const size_t obase = (size_t)(b * MM + qr0 + m) * CC + h * DD + d0;
#pragma unroll
        for (int j = 0; j < 8; ++j) {
            const int idx = m * 64 + d0 + j;
            float v = rbuf[idx] + rbuf[2048 + idx] + rbuf[4096 + idx] + rbuf[6144 + idx];
            out0[obase + j] = v + qtok[obase + j];
        }
    }
#undef STAGEK
#undef STAGEV
}

extern "C" void kernel_launch(void* const* d_in, const int* in_sizes, int n_in,
                              void* d_out, int out_size, void* d_ws, size_t ws_size,
                              hipStream_t stream) {
    (void)in_sizes; (void)n_in; (void)out_size; (void)ws_size;
    const float* input_tokens = (const float*)d_in[0];
    const float* query_tokens = (const float*)d_in[1];
    const float* Wq   = (const float*)d_in[2];
    const float* bq   = (const float*)d_in[3];
    const float* Wk   = (const float*)d_in[4];
    const float* bk   = (const float*)d_in[5];
    const float* Wv   = (const float*)d_in[6];
    const float* bv   = (const float*)d_in[7];
    const float* gq   = (const float*)d_in[8];
    const float* bqln = (const float*)d_in[9];
    const float* gk   = (const float*)d_in[10];
    const float* bkln = (const float*)d_in[11];

    float* out0 = (float*)d_out;
    float* attn = out0 + (size_t)BB * MM * CC;

    float* ws    = (float*)d_ws;
    float* Klin  = ws;                                  // 12.58M f32
    float* Qlin  = Klin + (size_t)BB * NN * CC;         // 0.79M f32
    unsigned short* Xb   = (unsigned short*)(Qlin + (size_t)BB * MM * CC);
    unsigned short* X2b  = Xb   + (size_t)BB * NN * CC;
    unsigned short* Wkb2 = X2b  + (size_t)BB * MM * CC;
    unsigned short* Wqb2 = Wkb2 + (size_t)CC * 1536;
    unsigned short* Wvb  = Wqb2 + (size_t)CC * 1536;
    _Float16* Kh = (_Float16*)(Wvb + (size_t)CC * CC);  // [B][N][C] f16
    _Float16* Qh = Kh + (size_t)BB * NN * CC;           // [B][M][C] f16
    _Float16* Vt = Qh + (size_t)BB * MM * CC;           // [48][64][4096] f16

    // --- convert inputs/weights to bf16 ---
    conv_bf16<<<2048, 256, 0, stream>>>(input_tokens, Xb, (long long)BB * NN * CC);
    conv_bf16<<<384, 256, 0, stream>>>(query_tokens, X2b, (long long)BB * MM * CC);
    conv_bf16<<<288, 256, 0, stream>>>(Wv, Wvb, (long long)CC * CC);
    conv_w_split<<<(CC * CC) / 256, 256, 0, stream>>>(Wk, Wkb2);
    conv_w_split<<<(CC * CC) / 256, 256, 0, stream>>>(Wq, Wqb2);

    // --- all three projections in one MFMA dispatch (V -> fp16 transposed) ---
    proj_gemm_mfma<<<1584, 256, 0, stream>>>(Xb, X2b, Wkb2, Wqb2, Wvb,
                                             bk, bq, bv, Klin, Qlin, Vt);

    // --- LayerNorm -> fp16 (scale folded into Q) ---
    ln_rows_f16<<<BB * NN, 256, 0, stream>>>(Klin, Kh, gk, bkln, 1.0f);
    ln_rows_f16<<<BB * MM, 256, 0, stream>>>(Qlin, Qh, gq, bqln, SCALEF);

    // --- fused flash attention (writes attn probs + out0 with residual) ---
    fused_attn<<<BB * HH * (MM / 32), 256, 0, stream>>>(Qh, Kh, Vt, query_tokens,
                                                        attn, out0);
}